// Round 5
// baseline (288.343 us; speedup 1.0000x reference)
//
#include <hip/hip_runtime.h>

#define N_EDGES  800000
#define N_NODES  50000
#define IN_DIM   64
#define EDGE_DIM 32
#define HID      96
#define OUT_DIM  64
#define BE       128              // edges per tile
#define PAD      104              // LDS row length (bf16): 208 B rows, 16B-aligned, 2-way banks (free)
#define NTILES   (N_EDGES / BE)   // 6250 exactly
#define THREADS  512
#define GRID     512              // 2 blocks/CU, persistent

typedef __attribute__((ext_vector_type(8))) short  short8;
typedef __attribute__((ext_vector_type(4))) ushort bf16x4;
typedef __attribute__((ext_vector_type(4))) float  f32x4;

__device__ inline ushort f2bf(float f) {
    union { float f; unsigned u; } v; v.f = f;
    unsigned r = v.u + 0x7FFFu + ((v.u >> 16) & 1u);   // round-to-nearest-even
    return (ushort)(r >> 16);
}
__device__ inline float b2f(ushort u) {
    union { unsigned u; float f; } v; v.u = ((unsigned)u) << 16;
    return v.f;
}

// ---------------------------------------------------------------------------
// CSR-build kernels (cheap: ~1.6M int atomics total vs 51.2M fp32 before)
// ---------------------------------------------------------------------------
__global__ __launch_bounds__(256) void zero_hist_kernel(int* __restrict__ hist) {
    int i = blockIdx.x * 256 + threadIdx.x;
    if (i < N_NODES) hist[i] = 0;
}

__global__ __launch_bounds__(256) void hist_kernel(const int* __restrict__ ei,
                                                   int* __restrict__ hist) {
    int e = blockIdx.x * 256 + threadIdx.x;
    if (e < N_EDGES) atomicAdd(&hist[ei[N_EDGES + e]], 1);
}

// single-block chunked Hillis-Steele scan over 50k counts -> starts & cursor
__global__ __launch_bounds__(1024) void scan_kernel(const int* __restrict__ hist,
                                                    int* __restrict__ starts,
                                                    int* __restrict__ cursor) {
    __shared__ int buf[1024];
    __shared__ int carry_s;
    const int tid = threadIdx.x;
    if (tid == 0) carry_s = 0;
    __syncthreads();
    for (int base = 0; base < N_NODES; base += 1024) {
        int v = (base + tid < N_NODES) ? hist[base + tid] : 0;
        buf[tid] = v;
        __syncthreads();
        #pragma unroll
        for (int off = 1; off < 1024; off <<= 1) {
            int t = (tid >= off) ? buf[tid - off] : 0;
            __syncthreads();
            buf[tid] += t;
            __syncthreads();
        }
        int incl = buf[tid];
        if (base + tid < N_NODES) {
            int excl = carry_s + incl - v;
            starts[base + tid] = excl;
            cursor[base + tid] = excl;
        }
        __syncthreads();                 // everyone read carry_s before update
        if (tid == 1023) carry_s += buf[1023];
        __syncthreads();
    }
}

__global__ __launch_bounds__(256) void fill_kernel(const int* __restrict__ ei,
                                                   int* __restrict__ cursor,
                                                   int* __restrict__ ids) {
    int e = blockIdx.x * 256 + threadIdx.x;
    if (e < N_EDGES) {
        int c = ei[N_EDGES + e];
        int p = atomicAdd(&cursor[c], 1);
        ids[p] = e;
    }
}

// ---------------------------------------------------------------------------
// Fallback-path helpers (used only if ws_size can't hold the temp buffer)
// ---------------------------------------------------------------------------
__global__ __launch_bounds__(256) void zero_kernel(float* __restrict__ out,
                                                   float* __restrict__ cnt) {
    int i = blockIdx.x * 256 + threadIdx.x;
    if (i < N_NODES * OUT_DIM) out[i] = 0.0f;
    if (i < N_NODES) cnt[i] = 0.0f;
}

__global__ __launch_bounds__(256) void div_kernel(float* __restrict__ out,
                                                  const float* __restrict__ cnt) {
    int i = blockIdx.x * 256 + threadIdx.x;
    if (i < N_NODES * OUT_DIM) {
        float c = cnt[i / OUT_DIM];
        out[i] = out[i] / fmaxf(c, 1.0f);
    }
}

// ---------------------------------------------------------------------------
// Fused gather -> bf16 MFMA MLP. ATOMIC=true: scatter via atomics (fallback).
// ATOMIC=false: coalesced bf16 store of per-edge output rows to temp[E][64].
// 8 waves share one LDS weight copy; each wave owns 16 edge-rows end-to-end
// (no __syncthreads in tile loop; lgkmcnt(0) fences cross-lane LDS handoffs).
// ---------------------------------------------------------------------------
template <bool ATOMIC>
__global__ __launch_bounds__(THREADS, 4) void edge_mlp_mfma_kernel(
    const float* __restrict__ x,
    const int*   __restrict__ ei,     // [2, E] int32
    const float* __restrict__ ea,
    const float* __restrict__ W1,     // [HID, HID] row-major (k, n)
    const float* __restrict__ b1,
    const float* __restrict__ W2,     // [HID, OUT] row-major (k, n)
    const float* __restrict__ b2,
    float*       __restrict__ out,    // [N, OUT] accumulator (ATOMIC only)
    float*       __restrict__ cnt,    // [N] (ATOMIC only)
    ushort*      __restrict__ temp)   // [E, OUT] bf16 (!ATOMIC only)
{
    __shared__ ushort sA[BE][PAD];        // input tile, then H, then O (reused)
    __shared__ ushort sW1T[HID][PAD];     // W1 transposed: [n][k]
    __shared__ ushort sW2T[OUT_DIM][PAD]; // W2 transposed: [n][k]

    const int tid  = threadIdx.x;
    const int wave = tid >> 6;
    const int lane = tid & 63;
    const int lr   = lane & 15;
    const int lg   = lane >> 4;
    const int el_base = wave * 16;

    // ---- stage weights (bf16, transposed), float4-vectorized ----
    #pragma unroll 2
    for (int i = tid; i < HID * HID / 4; i += THREADS) {
        float4 v = reinterpret_cast<const float4*>(W1)[i];
        int k = (i * 4) / HID, n = (i * 4) % HID;
        sW1T[n + 0][k] = f2bf(v.x); sW1T[n + 1][k] = f2bf(v.y);
        sW1T[n + 2][k] = f2bf(v.z); sW1T[n + 3][k] = f2bf(v.w);
    }
    #pragma unroll 2
    for (int i = tid; i < HID * OUT_DIM / 4; i += THREADS) {
        float4 v = reinterpret_cast<const float4*>(W2)[i];
        int k = (i * 4) / OUT_DIM, n = (i * 4) % OUT_DIM;
        sW2T[n + 0][k] = f2bf(v.x); sW2T[n + 1][k] = f2bf(v.y);
        sW2T[n + 2][k] = f2bf(v.z); sW2T[n + 3][k] = f2bf(v.w);
    }
    float rb1[6], rb2[4];
    #pragma unroll
    for (int nt = 0; nt < 6; ++nt) rb1[nt] = b1[nt * 16 + lr];
    #pragma unroll
    for (int nt = 0; nt < 4; ++nt) rb2[nt] = b2[nt * 16 + lr];
    __syncthreads();

    for (int tl = blockIdx.x; tl < NTILES; tl += gridDim.x) {
        const int e0 = tl * BE;

        // ---- gather: 4 lanes per edge, 6 float4 each ----
        {
            const int el   = el_base + (lane >> 2);
            const int part = lane & 3;
            const int e    = e0 + el;
            const int src  = ei[e];
            const float4* xp = reinterpret_cast<const float4*>(x) + (size_t)src * 16;
            const float4* ep = reinterpret_cast<const float4*>(ea) + (size_t)e * 8;
            #pragma unroll
            for (int i = 0; i < 6; ++i) {
                const int f = part + 4 * i;
                float4 v = (i < 4) ? xp[f] : ep[f - 16];
                bf16x4 w = { f2bf(v.x), f2bf(v.y), f2bf(v.z), f2bf(v.w) };
                *(bf16x4*)&sA[el][f * 4] = w;
            }
            if constexpr (ATOMIC) {
                if (part == 0) atomicAdd(cnt + ei[N_EDGES + e], 1.0f);
            }
        }
        asm volatile("s_waitcnt lgkmcnt(0)" ::: "memory");
        __builtin_amdgcn_sched_barrier(0);

        // ---- GEMM1: H = relu(A @ W1 + b1) ----
        short8 af[3];
        #pragma unroll
        for (int ks = 0; ks < 3; ++ks)
            af[ks] = *(const short8*)&sA[el_base + lr][ks * 32 + lg * 8];

        f32x4 acc1[6];
        #pragma unroll
        for (int nt = 0; nt < 6; ++nt) {
            float bv = rb1[nt];
            acc1[nt] = f32x4{ bv, bv, bv, bv };
        }
        #pragma unroll
        for (int nt = 0; nt < 6; ++nt) {
            short8 bf[3];
            #pragma unroll
            for (int ks = 0; ks < 3; ++ks)
                bf[ks] = *(const short8*)&sW1T[nt * 16 + lr][ks * 32 + lg * 8];
            #pragma unroll
            for (int ks = 0; ks < 3; ++ks)
                acc1[nt] = __builtin_amdgcn_mfma_f32_16x16x32_bf16(
                    af[ks], bf[ks], acc1[nt], 0, 0, 0);
        }

        // ---- ReLU + write H back over sA (D layout: col=lr, row=lg*4+j) ----
        #pragma unroll
        for (int nt = 0; nt < 6; ++nt)
            #pragma unroll
            for (int j = 0; j < 4; ++j)
                sA[el_base + lg * 4 + j][nt * 16 + lr] =
                    f2bf(fmaxf(acc1[nt][j], 0.0f));
        asm volatile("s_waitcnt lgkmcnt(0)" ::: "memory");
        __builtin_amdgcn_sched_barrier(0);

        // ---- GEMM2: O = H @ W2 + b2 ----
        short8 a2[3];
        #pragma unroll
        for (int ks = 0; ks < 3; ++ks)
            a2[ks] = *(const short8*)&sA[el_base + lr][ks * 32 + lg * 8];

        f32x4 acc2[4];
        #pragma unroll
        for (int nt = 0; nt < 4; ++nt) {
            float bv = rb2[nt];
            acc2[nt] = f32x4{ bv, bv, bv, bv };
        }
        #pragma unroll
        for (int nt = 0; nt < 4; ++nt) {
            short8 bf[3];
            #pragma unroll
            for (int ks = 0; ks < 3; ++ks)
                bf[ks] = *(const short8*)&sW2T[nt * 16 + lr][ks * 32 + lg * 8];
            #pragma unroll
            for (int ks = 0; ks < 3; ++ks)
                acc2[nt] = __builtin_amdgcn_mfma_f32_16x16x32_bf16(
                    a2[ks], bf[ks], acc2[nt], 0, 0, 0);
        }

        if constexpr (ATOMIC) {
            // ---- scatter: out[col[e]][o] += acc2 ----
            int nd[4];
            #pragma unroll
            for (int j = 0; j < 4; ++j)
                nd[j] = ei[N_EDGES + e0 + el_base + lg * 4 + j];
            #pragma unroll
            for (int nt = 0; nt < 4; ++nt)
                #pragma unroll
                for (int j = 0; j < 4; ++j)
                    atomicAdd(out + (size_t)nd[j] * OUT_DIM + nt * 16 + lr,
                              acc2[nt][j]);
        } else {
            // ---- bounce O through sA (bf16), then coalesced stores to temp ----
            #pragma unroll
            for (int nt = 0; nt < 4; ++nt)
                #pragma unroll
                for (int j = 0; j < 4; ++j)
                    sA[el_base + lg * 4 + j][nt * 16 + lr] = f2bf(acc2[nt][j]);
            asm volatile("s_waitcnt lgkmcnt(0)" ::: "memory");
            __builtin_amdgcn_sched_barrier(0);
            const int rr = lane >> 2, pp = lane & 3;          // 4 lanes per row
            ushort* dst = temp + (size_t)(e0 + el_base + rr) * OUT_DIM + pp * 16;
            short8 v0 = *(const short8*)&sA[el_base + rr][pp * 16];
            short8 v1 = *(const short8*)&sA[el_base + rr][pp * 16 + 8];
            *(short8*)dst = v0;
            *(short8*)(dst + 8) = v1;
        }
    }
}

// ---------------------------------------------------------------------------
// Pull: one wave per node, lane = output dim; fp32 register sum, /deg.
// ---------------------------------------------------------------------------
__global__ __launch_bounds__(256) void pull_kernel(const ushort* __restrict__ temp,
                                                   const int* __restrict__ ids,
                                                   const int* __restrict__ starts,
                                                   const int* __restrict__ hist,
                                                   float* __restrict__ out) {
    const int wave = threadIdx.x >> 6;
    const int lane = threadIdx.x & 63;
    const int node = blockIdx.x * 4 + wave;
    if (node >= N_NODES) return;
    const int deg = hist[node];
    const int st  = starts[node];
    float s = 0.0f;
    int i = 0;
    for (; i + 4 <= deg; i += 4) {
        int e0 = ids[st + i], e1 = ids[st + i + 1];
        int e2 = ids[st + i + 2], e3 = ids[st + i + 3];
        float a = b2f(temp[(size_t)e0 * OUT_DIM + lane]);
        float b = b2f(temp[(size_t)e1 * OUT_DIM + lane]);
        float c = b2f(temp[(size_t)e2 * OUT_DIM + lane]);
        float d = b2f(temp[(size_t)e3 * OUT_DIM + lane]);
        s += (a + b) + (c + d);
    }
    for (; i < deg; ++i)
        s += b2f(temp[(size_t)ids[st + i] * OUT_DIM + lane]);
    out[(size_t)node * OUT_DIM + lane] = s / fmaxf((float)deg, 1.0f);
}

extern "C" void kernel_launch(void* const* d_in, const int* in_sizes, int n_in,
                              void* d_out, int out_size, void* d_ws, size_t ws_size,
                              hipStream_t stream) {
    const float* x  = (const float*)d_in[0];
    const int*   ei = (const int*)d_in[1];
    const float* ea = (const float*)d_in[2];
    const float* W1 = (const float*)d_in[3];
    const float* b1 = (const float*)d_in[4];
    const float* W2 = (const float*)d_in[5];
    const float* b2 = (const float*)d_in[6];
    float* out = (float*)d_out;

    // ws layout: temp[E*64] bf16 | ids[E] | hist[N] | starts[N] | cursor[N]
    char* ws = (char*)d_ws;
    const size_t tempB   = (size_t)N_EDGES * OUT_DIM * sizeof(ushort); // 102.4 MB
    const size_t idsOff  = tempB;
    const size_t histOff = idsOff + (size_t)N_EDGES * 4;
    const size_t strOff  = histOff + (size_t)N_NODES * 4;
    const size_t curOff  = strOff + (size_t)N_NODES * 4;
    const size_t need    = curOff + (size_t)N_NODES * 4;

    if (ws_size >= need) {
        ushort* temp  = (ushort*)ws;
        int* ids      = (int*)(ws + idsOff);
        int* hist     = (int*)(ws + histOff);
        int* starts   = (int*)(ws + strOff);
        int* cursor   = (int*)(ws + curOff);

        zero_hist_kernel<<<(N_NODES + 255) / 256, 256, 0, stream>>>(hist);
        hist_kernel<<<N_EDGES / 256, 256, 0, stream>>>(ei, hist);
        scan_kernel<<<1, 1024, 0, stream>>>(hist, starts, cursor);
        fill_kernel<<<N_EDGES / 256, 256, 0, stream>>>(ei, cursor, ids);
        edge_mlp_mfma_kernel<false><<<GRID, THREADS, 0, stream>>>(
            x, ei, ea, W1, b1, W2, b2, out, nullptr, temp);
        pull_kernel<<<(N_NODES + 3) / 4, 256, 0, stream>>>(temp, ids, starts, hist, out);
    } else {
        // fallback: atomic scatter path (round-4 behavior)
        float* cnt = (float*)d_ws;  // N_NODES floats
        zero_kernel<<<(N_NODES * OUT_DIM + 255) / 256, 256, 0, stream>>>(out, cnt);
        edge_mlp_mfma_kernel<true><<<GRID, THREADS, 0, stream>>>(
            x, ei, ea, W1, b1, W2, b2, out, cnt, nullptr);
        div_kernel<<<(N_NODES * OUT_DIM + 255) / 256, 256, 0, stream>>>(out, cnt);
    }
}

// Round 6
// 204.021 us; speedup vs baseline: 1.4133x; 1.4133x over previous
//
#include <hip/hip_runtime.h>

#define N_EDGES  800000
#define N_NODES  50000
#define IN_DIM   64
#define EDGE_DIM 32
#define HID      96
#define OUT_DIM  64
#define BE       128              // edges per tile
#define PAD      104              // LDS row length (bf16): 208 B rows, 16B-aligned, 2-way banks (free)
#define NTILES   (N_EDGES / BE)   // 6250 exactly
#define THREADS  512
#define GRID     512              // 2 blocks/CU, persistent
#define SCAN_B   1024
#define SCAN_NB  ((N_NODES + SCAN_B - 1) / SCAN_B)   // 49

typedef __attribute__((ext_vector_type(8))) short  short8;
typedef __attribute__((ext_vector_type(4))) ushort bf16x4;
typedef __attribute__((ext_vector_type(4))) float  f32x4;

__device__ inline ushort f2bf(float f) {
    union { float f; unsigned u; } v; v.f = f;
    unsigned r = v.u + 0x7FFFu + ((v.u >> 16) & 1u);   // round-to-nearest-even
    return (ushort)(r >> 16);
}
__device__ inline float b2f(ushort u) {
    union { unsigned u; float f; } v; v.u = ((unsigned)u) << 16;
    return v.f;
}

// ---------------------------------------------------------------------------
// CSR-build kernels
// ---------------------------------------------------------------------------
__global__ __launch_bounds__(256) void zero_hist_kernel(int* __restrict__ hist) {
    int i = blockIdx.x * 256 + threadIdx.x;
    if (i < N_NODES) hist[i] = 0;
}

__global__ __launch_bounds__(256) void hist_kernel(const int* __restrict__ ei,
                                                   int* __restrict__ hist) {
    int e = blockIdx.x * 256 + threadIdx.x;
    if (e < N_EDGES) atomicAdd(&hist[ei[N_EDGES + e]], 1);
}

// scan1: per-block inclusive Hillis-Steele; incl -> starts (in-place temp),
// block totals -> bsums.  49 blocks x 1024 threads.
__global__ __launch_bounds__(SCAN_B) void scan1_kernel(const int* __restrict__ hist,
                                                       int* __restrict__ starts,
                                                       int* __restrict__ bsums) {
    __shared__ int buf[2][SCAN_B];
    const int tid = threadIdx.x;
    const int gid = blockIdx.x * SCAN_B + tid;
    int v = (gid < N_NODES) ? hist[gid] : 0;
    int cur = 0;
    buf[0][tid] = v;
    __syncthreads();
    #pragma unroll
    for (int off = 1; off < SCAN_B; off <<= 1) {
        int t = buf[cur][tid] + ((tid >= off) ? buf[cur][tid - off] : 0);
        buf[cur ^ 1][tid] = t;
        __syncthreads();
        cur ^= 1;
    }
    int incl = buf[cur][tid];
    if (gid < N_NODES) starts[gid] = incl;
    if (tid == SCAN_B - 1) bsums[blockIdx.x] = incl;
}

// scan2: exclusive scan of 49 block sums (serial, trivial)
__global__ __launch_bounds__(64) void scan2_kernel(int* __restrict__ bsums) {
    if (threadIdx.x == 0) {
        int acc = 0;
        for (int i = 0; i < SCAN_NB; ++i) { int t = bsums[i]; bsums[i] = acc; acc += t; }
    }
}

// scan3: global exclusive = incl - v + block offset -> starts & cursor
__global__ __launch_bounds__(SCAN_B) void scan3_kernel(const int* __restrict__ hist,
                                                       int* __restrict__ starts,
                                                       int* __restrict__ cursor,
                                                       const int* __restrict__ bsums) {
    const int gid = blockIdx.x * SCAN_B + threadIdx.x;
    if (gid < N_NODES) {
        int e = starts[gid] - hist[gid] + bsums[blockIdx.x];
        starts[gid] = e;
        cursor[gid] = e;
    }
}

__global__ __launch_bounds__(256) void fill_kernel(const int* __restrict__ ei,
                                                   int* __restrict__ cursor,
                                                   int* __restrict__ ids) {
    int e = blockIdx.x * 256 + threadIdx.x;
    if (e < N_EDGES) {
        int c = ei[N_EDGES + e];
        int p = atomicAdd(&cursor[c], 1);
        ids[p] = e;
    }
}

// ---------------------------------------------------------------------------
// Fallback-path helpers (used only if ws_size can't hold the temp buffer)
// ---------------------------------------------------------------------------
__global__ __launch_bounds__(256) void zero_kernel(float* __restrict__ out,
                                                   float* __restrict__ cnt) {
    int i = blockIdx.x * 256 + threadIdx.x;
    if (i < N_NODES * OUT_DIM) out[i] = 0.0f;
    if (i < N_NODES) cnt[i] = 0.0f;
}

__global__ __launch_bounds__(256) void div_kernel(float* __restrict__ out,
                                                  const float* __restrict__ cnt) {
    int i = blockIdx.x * 256 + threadIdx.x;
    if (i < N_NODES * OUT_DIM) {
        float c = cnt[i / OUT_DIM];
        out[i] = out[i] / fmaxf(c, 1.0f);
    }
}

// ---------------------------------------------------------------------------
// Fused gather -> bf16 MFMA MLP. ATOMIC=true: scatter via atomics (fallback).
// ATOMIC=false: coalesced bf16 store of per-edge output rows to temp[E][64].
// ---------------------------------------------------------------------------
template <bool ATOMIC>
__global__ __launch_bounds__(THREADS, 4) void edge_mlp_mfma_kernel(
    const float* __restrict__ x,
    const int*   __restrict__ ei,     // [2, E] int32
    const float* __restrict__ ea,
    const float* __restrict__ W1,     // [HID, HID] row-major (k, n)
    const float* __restrict__ b1,
    const float* __restrict__ W2,     // [HID, OUT] row-major (k, n)
    const float* __restrict__ b2,
    float*       __restrict__ out,    // [N, OUT] accumulator (ATOMIC only)
    float*       __restrict__ cnt,    // [N] (ATOMIC only)
    ushort*      __restrict__ temp)   // [E, OUT] bf16 (!ATOMIC only)
{
    __shared__ ushort sA[BE][PAD];        // input tile, then H, then O (reused)
    __shared__ ushort sW1T[HID][PAD];     // W1 transposed: [n][k]
    __shared__ ushort sW2T[OUT_DIM][PAD]; // W2 transposed: [n][k]

    const int tid  = threadIdx.x;
    const int wave = tid >> 6;
    const int lane = tid & 63;
    const int lr   = lane & 15;
    const int lg   = lane >> 4;
    const int el_base = wave * 16;

    // ---- stage weights (bf16, transposed), float4-vectorized ----
    #pragma unroll 2
    for (int i = tid; i < HID * HID / 4; i += THREADS) {
        float4 v = reinterpret_cast<const float4*>(W1)[i];
        int k = (i * 4) / HID, n = (i * 4) % HID;
        sW1T[n + 0][k] = f2bf(v.x); sW1T[n + 1][k] = f2bf(v.y);
        sW1T[n + 2][k] = f2bf(v.z); sW1T[n + 3][k] = f2bf(v.w);
    }
    #pragma unroll 2
    for (int i = tid; i < HID * OUT_DIM / 4; i += THREADS) {
        float4 v = reinterpret_cast<const float4*>(W2)[i];
        int k = (i * 4) / OUT_DIM, n = (i * 4) % OUT_DIM;
        sW2T[n + 0][k] = f2bf(v.x); sW2T[n + 1][k] = f2bf(v.y);
        sW2T[n + 2][k] = f2bf(v.z); sW2T[n + 3][k] = f2bf(v.w);
    }
    float rb1[6], rb2[4];
    #pragma unroll
    for (int nt = 0; nt < 6; ++nt) rb1[nt] = b1[nt * 16 + lr];
    #pragma unroll
    for (int nt = 0; nt < 4; ++nt) rb2[nt] = b2[nt * 16 + lr];
    __syncthreads();

    for (int tl = blockIdx.x; tl < NTILES; tl += gridDim.x) {
        const int e0 = tl * BE;

        // ---- gather: 4 lanes per edge, 6 float4 each ----
        {
            const int el   = el_base + (lane >> 2);
            const int part = lane & 3;
            const int e    = e0 + el;
            const int src  = ei[e];
            const float4* xp = reinterpret_cast<const float4*>(x) + (size_t)src * 16;
            const float4* ep = reinterpret_cast<const float4*>(ea) + (size_t)e * 8;
            #pragma unroll
            for (int i = 0; i < 6; ++i) {
                const int f = part + 4 * i;
                float4 v = (i < 4) ? xp[f] : ep[f - 16];
                bf16x4 w = { f2bf(v.x), f2bf(v.y), f2bf(v.z), f2bf(v.w) };
                *(bf16x4*)&sA[el][f * 4] = w;
            }
            if constexpr (ATOMIC) {
                if (part == 0) atomicAdd(cnt + ei[N_EDGES + e], 1.0f);
            }
        }
        asm volatile("s_waitcnt lgkmcnt(0)" ::: "memory");
        __builtin_amdgcn_sched_barrier(0);

        // ---- GEMM1: H = relu(A @ W1 + b1) ----
        short8 af[3];
        #pragma unroll
        for (int ks = 0; ks < 3; ++ks)
            af[ks] = *(const short8*)&sA[el_base + lr][ks * 32 + lg * 8];

        f32x4 acc1[6];
        #pragma unroll
        for (int nt = 0; nt < 6; ++nt) {
            float bv = rb1[nt];
            acc1[nt] = f32x4{ bv, bv, bv, bv };
        }
        #pragma unroll
        for (int nt = 0; nt < 6; ++nt) {
            short8 bf[3];
            #pragma unroll
            for (int ks = 0; ks < 3; ++ks)
                bf[ks] = *(const short8*)&sW1T[nt * 16 + lr][ks * 32 + lg * 8];
            #pragma unroll
            for (int ks = 0; ks < 3; ++ks)
                acc1[nt] = __builtin_amdgcn_mfma_f32_16x16x32_bf16(
                    af[ks], bf[ks], acc1[nt], 0, 0, 0);
        }

        // ---- ReLU + write H back over sA (D layout: col=lr, row=lg*4+j) ----
        #pragma unroll
        for (int nt = 0; nt < 6; ++nt)
            #pragma unroll
            for (int j = 0; j < 4; ++j)
                sA[el_base + lg * 4 + j][nt * 16 + lr] =
                    f2bf(fmaxf(acc1[nt][j], 0.0f));
        asm volatile("s_waitcnt lgkmcnt(0)" ::: "memory");
        __builtin_amdgcn_sched_barrier(0);

        // ---- GEMM2: O = H @ W2 + b2 ----
        short8 a2[3];
        #pragma unroll
        for (int ks = 0; ks < 3; ++ks)
            a2[ks] = *(const short8*)&sA[el_base + lr][ks * 32 + lg * 8];

        f32x4 acc2[4];
        #pragma unroll
        for (int nt = 0; nt < 4; ++nt) {
            float bv = rb2[nt];
            acc2[nt] = f32x4{ bv, bv, bv, bv };
        }
        #pragma unroll
        for (int nt = 0; nt < 4; ++nt) {
            short8 bf[3];
            #pragma unroll
            for (int ks = 0; ks < 3; ++ks)
                bf[ks] = *(const short8*)&sW2T[nt * 16 + lr][ks * 32 + lg * 8];
            #pragma unroll
            for (int ks = 0; ks < 3; ++ks)
                acc2[nt] = __builtin_amdgcn_mfma_f32_16x16x32_bf16(
                    a2[ks], bf[ks], acc2[nt], 0, 0, 0);
        }

        if constexpr (ATOMIC) {
            int nd[4];
            #pragma unroll
            for (int j = 0; j < 4; ++j)
                nd[j] = ei[N_EDGES + e0 + el_base + lg * 4 + j];
            #pragma unroll
            for (int nt = 0; nt < 4; ++nt)
                #pragma unroll
                for (int j = 0; j < 4; ++j)
                    atomicAdd(out + (size_t)nd[j] * OUT_DIM + nt * 16 + lr,
                              acc2[nt][j]);
        } else {
            // ---- bounce O through sA (bf16), then coalesced stores to temp ----
            #pragma unroll
            for (int nt = 0; nt < 4; ++nt)
                #pragma unroll
                for (int j = 0; j < 4; ++j)
                    sA[el_base + lg * 4 + j][nt * 16 + lr] = f2bf(acc2[nt][j]);
            asm volatile("s_waitcnt lgkmcnt(0)" ::: "memory");
            __builtin_amdgcn_sched_barrier(0);
            const int rr = lane >> 2, pp = lane & 3;          // 4 lanes per row
            ushort* dst = temp + (size_t)(e0 + el_base + rr) * OUT_DIM + pp * 16;
            short8 v0 = *(const short8*)&sA[el_base + rr][pp * 16];
            short8 v1 = *(const short8*)&sA[el_base + rr][pp * 16 + 8];
            *(short8*)dst = v0;
            *(short8*)(dst + 8) = v1;
        }
    }
}

// ---------------------------------------------------------------------------
// Pull: one wave per node, lane = output dim; fp32 register sum, /deg.
// ---------------------------------------------------------------------------
__global__ __launch_bounds__(256) void pull_kernel(const ushort* __restrict__ temp,
                                                   const int* __restrict__ ids,
                                                   const int* __restrict__ starts,
                                                   const int* __restrict__ hist,
                                                   float* __restrict__ out) {
    const int wave = threadIdx.x >> 6;
    const int lane = threadIdx.x & 63;
    const int node = blockIdx.x * 4 + wave;
    if (node >= N_NODES) return;
    const int deg = hist[node];
    const int st  = starts[node];
    float s = 0.0f;
    int i = 0;
    for (; i + 4 <= deg; i += 4) {
        int e0 = ids[st + i], e1 = ids[st + i + 1];
        int e2 = ids[st + i + 2], e3 = ids[st + i + 3];
        float a = b2f(temp[(size_t)e0 * OUT_DIM + lane]);
        float b = b2f(temp[(size_t)e1 * OUT_DIM + lane]);
        float c = b2f(temp[(size_t)e2 * OUT_DIM + lane]);
        float d = b2f(temp[(size_t)e3 * OUT_DIM + lane]);
        s += (a + b) + (c + d);
    }
    for (; i < deg; ++i)
        s += b2f(temp[(size_t)ids[st + i] * OUT_DIM + lane]);
    out[(size_t)node * OUT_DIM + lane] = s / fmaxf((float)deg, 1.0f);
}

extern "C" void kernel_launch(void* const* d_in, const int* in_sizes, int n_in,
                              void* d_out, int out_size, void* d_ws, size_t ws_size,
                              hipStream_t stream) {
    const float* x  = (const float*)d_in[0];
    const int*   ei = (const int*)d_in[1];
    const float* ea = (const float*)d_in[2];
    const float* W1 = (const float*)d_in[3];
    const float* b1 = (const float*)d_in[4];
    const float* W2 = (const float*)d_in[5];
    const float* b2 = (const float*)d_in[6];
    float* out = (float*)d_out;

    // ws layout: temp[E*64] bf16 | ids[E] | hist[N] | starts[N] | cursor[N] | bsums[64]
    char* ws = (char*)d_ws;
    const size_t tempB    = (size_t)N_EDGES * OUT_DIM * sizeof(ushort); // 102.4 MB
    const size_t idsOff   = tempB;
    const size_t histOff  = idsOff + (size_t)N_EDGES * 4;
    const size_t strOff   = histOff + (size_t)N_NODES * 4;
    const size_t curOff   = strOff + (size_t)N_NODES * 4;
    const size_t bsumOff  = curOff + (size_t)N_NODES * 4;
    const size_t need     = bsumOff + 64 * 4;

    if (ws_size >= need) {
        ushort* temp  = (ushort*)ws;
        int* ids      = (int*)(ws + idsOff);
        int* hist     = (int*)(ws + histOff);
        int* starts   = (int*)(ws + strOff);
        int* cursor   = (int*)(ws + curOff);
        int* bsums    = (int*)(ws + bsumOff);

        zero_hist_kernel<<<(N_NODES + 255) / 256, 256, 0, stream>>>(hist);
        hist_kernel<<<N_EDGES / 256, 256, 0, stream>>>(ei, hist);
        scan1_kernel<<<SCAN_NB, SCAN_B, 0, stream>>>(hist, starts, bsums);
        scan2_kernel<<<1, 64, 0, stream>>>(bsums);
        scan3_kernel<<<SCAN_NB, SCAN_B, 0, stream>>>(hist, starts, cursor, bsums);
        fill_kernel<<<N_EDGES / 256, 256, 0, stream>>>(ei, cursor, ids);
        edge_mlp_mfma_kernel<false><<<GRID, THREADS, 0, stream>>>(
            x, ei, ea, W1, b1, W2, b2, out, nullptr, temp);
        pull_kernel<<<(N_NODES + 3) / 4, 256, 0, stream>>>(temp, ids, starts, hist, out);
    } else {
        // fallback: atomic scatter path
        float* cnt = (float*)d_ws;  // N_NODES floats
        zero_kernel<<<(N_NODES * OUT_DIM + 255) / 256, 256, 0, stream>>>(out, cnt);
        edge_mlp_mfma_kernel<true><<<GRID, THREADS, 0, stream>>>(
            x, ei, ea, W1, b1, W2, b2, out, cnt, nullptr);
        div_kernel<<<(N_NODES * OUT_DIM + 255) / 256, 256, 0, stream>>>(out, cnt);
    }
}

// Round 8
// 174.148 us; speedup vs baseline: 1.6557x; 1.1715x over previous
//
#include <hip/hip_runtime.h>

#define N_EDGES  800000
#define N_NODES  50000
#define IN_DIM   64
#define EDGE_DIM 32
#define HID      96
#define OUT_DIM  64
#define BE       128              // edges per tile
#define PAD      104              // LDS row stride (bf16): 208 B; b128 reads land 2-way (free)
#define NTILES   (N_EDGES / BE)   // 6250 exactly
#define THREADS  512
#define GRID     512              // 2 blocks/CU, persistent
#define SCAN_B   1024
#define SCAN_NB  ((N_NODES + SCAN_B - 1) / SCAN_B)   // 49

typedef __attribute__((ext_vector_type(8))) short  short8;
typedef __attribute__((ext_vector_type(4))) ushort bf16x4;
typedef __attribute__((ext_vector_type(4))) float  f32x4;

__device__ inline ushort f2bf(float f) {
    union { float f; unsigned u; } v; v.f = f;
    unsigned r = v.u + 0x7FFFu + ((v.u >> 16) & 1u);   // round-to-nearest-even
    return (ushort)(r >> 16);
}
__device__ inline float b2f(ushort u) {
    union { unsigned u; float f; } v; v.u = ((unsigned)u) << 16;
    return v.f;
}

// ---------------------------------------------------------------------------
// CSR-build kernels
// ---------------------------------------------------------------------------
__global__ __launch_bounds__(256) void hist_kernel(const int* __restrict__ ei,
                                                   int* __restrict__ hist) {
    int e = blockIdx.x * 256 + threadIdx.x;
    if (e < N_EDGES) atomicAdd(&hist[ei[N_EDGES + e]], 1);
}

// scan1: per-block inclusive Hillis-Steele; incl -> starts, block totals -> bsums
__global__ __launch_bounds__(SCAN_B) void scan1_kernel(const int* __restrict__ hist,
                                                       int* __restrict__ starts,
                                                       int* __restrict__ bsums) {
    __shared__ int buf[2][SCAN_B];
    const int tid = threadIdx.x;
    const int gid = blockIdx.x * SCAN_B + tid;
    int v = (gid < N_NODES) ? hist[gid] : 0;
    int cur = 0;
    buf[0][tid] = v;
    __syncthreads();
    #pragma unroll
    for (int off = 1; off < SCAN_B; off <<= 1) {
        int t = buf[cur][tid] + ((tid >= off) ? buf[cur][tid - off] : 0);
        buf[cur ^ 1][tid] = t;
        __syncthreads();
        cur ^= 1;
    }
    int incl = buf[cur][tid];
    if (gid < N_NODES) starts[gid] = incl;
    if (tid == SCAN_B - 1) bsums[blockIdx.x] = incl;
}

// scan3: block offset via in-kernel wave reduce of bsums (merged scan2),
// then global exclusive = incl - v + offset -> starts & cursor
__global__ __launch_bounds__(SCAN_B) void scan3_kernel(const int* __restrict__ hist,
                                                       int* __restrict__ starts,
                                                       int* __restrict__ cursor,
                                                       const int* __restrict__ bsums) {
    __shared__ int s_off;
    if (threadIdx.x < 64) {
        int v = ((int)threadIdx.x < (int)blockIdx.x) ? bsums[threadIdx.x] : 0;  // blockIdx.x<=48
        #pragma unroll
        for (int o = 32; o >= 1; o >>= 1) v += __shfl_xor(v, o, 64);
        if (threadIdx.x == 0) s_off = v;
    }
    __syncthreads();
    const int gid = blockIdx.x * SCAN_B + threadIdx.x;
    if (gid < N_NODES) {
        int e = starts[gid] - hist[gid] + s_off;
        starts[gid] = e;
        cursor[gid] = e;
    }
}

// fill: record each edge's CSR slot (epos), so the MLP can store permuted
__global__ __launch_bounds__(256) void fill_kernel(const int* __restrict__ ei,
                                                   int* __restrict__ cursor,
                                                   int* __restrict__ epos) {
    int e = blockIdx.x * 256 + threadIdx.x;
    if (e < N_EDGES) {
        int c = ei[N_EDGES + e];
        int p = atomicAdd(&cursor[c], 1);
        epos[e] = p;
    }
}

// ---------------------------------------------------------------------------
// Fallback-path helpers (used only if ws_size can't hold the temp buffer)
// ---------------------------------------------------------------------------
__global__ __launch_bounds__(256) void zero_kernel(float* __restrict__ out,
                                                   float* __restrict__ cnt) {
    int i = blockIdx.x * 256 + threadIdx.x;
    if (i < N_NODES * OUT_DIM) out[i] = 0.0f;
    if (i < N_NODES) cnt[i] = 0.0f;
}

__global__ __launch_bounds__(256) void div_kernel(float* __restrict__ out,
                                                  const float* __restrict__ cnt) {
    int i = blockIdx.x * 256 + threadIdx.x;
    if (i < N_NODES * OUT_DIM) {
        float c = cnt[i / OUT_DIM];
        out[i] = out[i] / fmaxf(c, 1.0f);
    }
}

// ---------------------------------------------------------------------------
// Fused gather -> bf16 MFMA MLP, depth-1 software-pipelined gather.
// ATOMIC=true: atomic scatter fallback. ATOMIC=false: store per-edge output
// row (bf16, 128 B) at its CSR slot epos[e] in temp -> pull reads sequential.
// ---------------------------------------------------------------------------
template <bool ATOMIC>
__global__ __launch_bounds__(THREADS, 4) void edge_mlp_mfma_kernel(
    const float* __restrict__ x,
    const int*   __restrict__ ei,     // [2, E] int32
    const float* __restrict__ ea,
    const float* __restrict__ W1,     // [HID, HID] row-major (k, n)
    const float* __restrict__ b1,
    const float* __restrict__ W2,     // [HID, OUT] row-major (k, n)
    const float* __restrict__ b2,
    float*       __restrict__ out,    // [N, OUT] accumulator (ATOMIC only)
    float*       __restrict__ cnt,    // [N] (ATOMIC only)
    ushort*      __restrict__ temp,   // [E, OUT] bf16 (!ATOMIC only)
    const int*   __restrict__ epos)   // [E] CSR slot (!ATOMIC only)
{
    __shared__ ushort sA[BE][PAD];        // input tile, then H, then O (reused)
    __shared__ ushort sW1T[HID][PAD];     // W1 transposed: [n][k]
    __shared__ ushort sW2T[OUT_DIM][PAD]; // W2 transposed: [n][k]

    const int tid  = threadIdx.x;
    const int wave = tid >> 6;
    const int lane = tid & 63;
    const int lr   = lane & 15;
    const int lg   = lane >> 4;
    const int el_base = wave * 16;
    const int el   = el_base + (lane >> 2);   // gather/store row owned by this lane
    const int part = lane & 3;

    // ---- stage weights (bf16, transposed), float4-vectorized ----
    #pragma unroll 2
    for (int i = tid; i < HID * HID / 4; i += THREADS) {
        float4 v = reinterpret_cast<const float4*>(W1)[i];
        int k = (i * 4) / HID, n = (i * 4) % HID;
        sW1T[n + 0][k] = f2bf(v.x); sW1T[n + 1][k] = f2bf(v.y);
        sW1T[n + 2][k] = f2bf(v.z); sW1T[n + 3][k] = f2bf(v.w);
    }
    #pragma unroll 2
    for (int i = tid; i < HID * OUT_DIM / 4; i += THREADS) {
        float4 v = reinterpret_cast<const float4*>(W2)[i];
        int k = (i * 4) / OUT_DIM, n = (i * 4) % OUT_DIM;
        sW2T[n + 0][k] = f2bf(v.x); sW2T[n + 1][k] = f2bf(v.y);
        sW2T[n + 2][k] = f2bf(v.z); sW2T[n + 3][k] = f2bf(v.w);
    }
    float rb1[6], rb2[4];
    #pragma unroll
    for (int nt = 0; nt < 6; ++nt) rb1[nt] = b1[nt * 16 + lr];
    #pragma unroll
    for (int nt = 0; nt < 4; ++nt) rb2[nt] = b2[nt * 16 + lr];
    __syncthreads();

    // ---- prologue: prefetch first tile into registers ----
    float4 px0, px1, px2, px3, pe0, pe1;
    int ppos = 0, pdst = 0;
    int tl = blockIdx.x;
    {
        const int e = tl * BE + el;
        const int src = ei[e];
        if constexpr (ATOMIC) pdst = ei[N_EDGES + e];
        else                  ppos = epos[e];
        const float4* xp = reinterpret_cast<const float4*>(x) + (size_t)src * 16;
        const float4* ep = reinterpret_cast<const float4*>(ea) + (size_t)e * 8;
        px0 = xp[part]; px1 = xp[part + 4]; px2 = xp[part + 8]; px3 = xp[part + 12];
        pe0 = ep[part]; pe1 = ep[part + 4];
    }

    for (; tl < NTILES; tl += GRID) {
        // ---- write the prefetched tile into sA (f = part + 4*i) ----
        {
            bf16x4 w;
            w = bf16x4{ f2bf(px0.x), f2bf(px0.y), f2bf(px0.z), f2bf(px0.w) };
            *(bf16x4*)&sA[el][(part +  0) * 4] = w;
            w = bf16x4{ f2bf(px1.x), f2bf(px1.y), f2bf(px1.z), f2bf(px1.w) };
            *(bf16x4*)&sA[el][(part +  4) * 4] = w;
            w = bf16x4{ f2bf(px2.x), f2bf(px2.y), f2bf(px2.z), f2bf(px2.w) };
            *(bf16x4*)&sA[el][(part +  8) * 4] = w;
            w = bf16x4{ f2bf(px3.x), f2bf(px3.y), f2bf(px3.z), f2bf(px3.w) };
            *(bf16x4*)&sA[el][(part + 12) * 4] = w;
            w = bf16x4{ f2bf(pe0.x), f2bf(pe0.y), f2bf(pe0.z), f2bf(pe0.w) };
            *(bf16x4*)&sA[el][(part + 16) * 4] = w;
            w = bf16x4{ f2bf(pe1.x), f2bf(pe1.y), f2bf(pe1.z), f2bf(pe1.w) };
            *(bf16x4*)&sA[el][(part + 20) * 4] = w;
        }
        const int cpos = ppos, cdst = pdst;
        if constexpr (ATOMIC) {
            if (part == 0) atomicAdd(cnt + cdst, 1.0f);
        }

        // ---- prefetch next tile (flies during the GEMM section) ----
        const int tn = tl + GRID;
        const bool have = (tn < NTILES);
        float4 nx0, nx1, nx2, nx3, ne0, ne1;
        int npos = 0, ndst = 0;
        if (have) {
            const int e = tn * BE + el;
            const int src = ei[e];
            if constexpr (ATOMIC) ndst = ei[N_EDGES + e];
            else                  npos = epos[e];
            const float4* xp = reinterpret_cast<const float4*>(x) + (size_t)src * 16;
            const float4* ep = reinterpret_cast<const float4*>(ea) + (size_t)e * 8;
            nx0 = xp[part]; nx1 = xp[part + 4]; nx2 = xp[part + 8]; nx3 = xp[part + 12];
            ne0 = ep[part]; ne1 = ep[part + 4];
        }

        asm volatile("s_waitcnt lgkmcnt(0)" ::: "memory");
        __builtin_amdgcn_sched_barrier(0);

        // ---- GEMM1: H = relu(A @ W1 + b1) ----
        short8 af[3];
        #pragma unroll
        for (int ks = 0; ks < 3; ++ks)
            af[ks] = *(const short8*)&sA[el_base + lr][ks * 32 + lg * 8];

        f32x4 acc1[6];
        #pragma unroll
        for (int nt = 0; nt < 6; ++nt) {
            float bv = rb1[nt];
            acc1[nt] = f32x4{ bv, bv, bv, bv };
        }
        #pragma unroll
        for (int nt = 0; nt < 6; ++nt) {
            short8 bf[3];
            #pragma unroll
            for (int ks = 0; ks < 3; ++ks)
                bf[ks] = *(const short8*)&sW1T[nt * 16 + lr][ks * 32 + lg * 8];
            #pragma unroll
            for (int ks = 0; ks < 3; ++ks)
                acc1[nt] = __builtin_amdgcn_mfma_f32_16x16x32_bf16(
                    af[ks], bf[ks], acc1[nt], 0, 0, 0);
        }

        // ---- ReLU + write H back over sA (D layout: col=lr, row=lg*4+j) ----
        #pragma unroll
        for (int nt = 0; nt < 6; ++nt)
            #pragma unroll
            for (int j = 0; j < 4; ++j)
                sA[el_base + lg * 4 + j][nt * 16 + lr] =
                    f2bf(fmaxf(acc1[nt][j], 0.0f));
        asm volatile("s_waitcnt lgkmcnt(0)" ::: "memory");
        __builtin_amdgcn_sched_barrier(0);

        // ---- GEMM2: O = H @ W2 + b2 ----
        short8 a2[3];
        #pragma unroll
        for (int ks = 0; ks < 3; ++ks)
            a2[ks] = *(const short8*)&sA[el_base + lr][ks * 32 + lg * 8];

        f32x4 acc2[4];
        #pragma unroll
        for (int nt = 0; nt < 4; ++nt) {
            float bv = rb2[nt];
            acc2[nt] = f32x4{ bv, bv, bv, bv };
        }
        #pragma unroll
        for (int nt = 0; nt < 4; ++nt) {
            short8 bf[3];
            #pragma unroll
            for (int ks = 0; ks < 3; ++ks)
                bf[ks] = *(const short8*)&sW2T[nt * 16 + lr][ks * 32 + lg * 8];
            #pragma unroll
            for (int ks = 0; ks < 3; ++ks)
                acc2[nt] = __builtin_amdgcn_mfma_f32_16x16x32_bf16(
                    a2[ks], bf[ks], acc2[nt], 0, 0, 0);
        }

        if constexpr (ATOMIC) {
            int nd[4];
            #pragma unroll
            for (int j = 0; j < 4; ++j)
                nd[j] = ei[N_EDGES + tl * BE + el_base + lg * 4 + j];
            #pragma unroll
            for (int nt = 0; nt < 4; ++nt)
                #pragma unroll
                for (int j = 0; j < 4; ++j)
                    atomicAdd(out + (size_t)nd[j] * OUT_DIM + nt * 16 + lr,
                              acc2[nt][j]);
        } else {
            // ---- bounce O through sA (bf16), then 128-B row store at CSR slot ----
            #pragma unroll
            for (int nt = 0; nt < 4; ++nt)
                #pragma unroll
                for (int j = 0; j < 4; ++j)
                    sA[el_base + lg * 4 + j][nt * 16 + lr] = f2bf(acc2[nt][j]);
            asm volatile("s_waitcnt lgkmcnt(0)" ::: "memory");
            __builtin_amdgcn_sched_barrier(0);
            ushort* dst = temp + (size_t)cpos * OUT_DIM + part * 16;
            short8 v0 = *(const short8*)&sA[el][part * 16];
            short8 v1 = *(const short8*)&sA[el][part * 16 + 8];
            *(short8*)dst = v0;
            *(short8*)(dst + 8) = v1;
        }

        // ---- rotate pipeline registers ----
        if (have) {
            px0 = nx0; px1 = nx1; px2 = nx2; px3 = nx3;
            pe0 = ne0; pe1 = ne1;
            ppos = npos; pdst = ndst;
        }
    }
}

// ---------------------------------------------------------------------------
// Pull: one wave per node; temp rows are CSR-contiguous. A row is 64 bf16 =
// 128 B = 16 uint2. Lane r=row-in-quad, g=uint2-in-row. (Round-7 bug: used
// stride 8 uint2/row instead of 16.)
// ---------------------------------------------------------------------------
__global__ __launch_bounds__(256) void pull_kernel(const ushort* __restrict__ temp,
                                                   const int* __restrict__ starts,
                                                   const int* __restrict__ hist,
                                                   float* __restrict__ out) {
    const int wave = threadIdx.x >> 6;
    const int lane = threadIdx.x & 63;
    const int node = blockIdx.x * 4 + wave;
    if (node >= N_NODES) return;
    const int deg = hist[node];
    const int st  = starts[node];
    const int r   = lane >> 4;     // row within quad
    const int g   = lane & 15;     // uint2 index within row (4 dims each)
    float sx = 0.f, sy = 0.f, sz = 0.f, sw = 0.f;
    const uint2* base = reinterpret_cast<const uint2*>(temp) + (size_t)st * 16 + g;
    for (int i = r; i < deg; i += 4) {
        uint2 u = base[(size_t)i * 16];
        sx += b2f((ushort)(u.x & 0xFFFFu));
        sy += b2f((ushort)(u.x >> 16));
        sz += b2f((ushort)(u.y & 0xFFFFu));
        sw += b2f((ushort)(u.y >> 16));
    }
    #pragma unroll
    for (int o = 16; o <= 32; o <<= 1) {
        sx += __shfl_xor(sx, o, 64);
        sy += __shfl_xor(sy, o, 64);
        sz += __shfl_xor(sz, o, 64);
        sw += __shfl_xor(sw, o, 64);
    }
    if (r == 0) {
        float inv = 1.0f / fmaxf((float)deg, 1.0f);
        float4 o4 = { sx * inv, sy * inv, sz * inv, sw * inv };
        *reinterpret_cast<float4*>(out + (size_t)node * OUT_DIM + g * 4) = o4;
    }
}

extern "C" void kernel_launch(void* const* d_in, const int* in_sizes, int n_in,
                              void* d_out, int out_size, void* d_ws, size_t ws_size,
                              hipStream_t stream) {
    const float* x  = (const float*)d_in[0];
    const int*   ei = (const int*)d_in[1];
    const float* ea = (const float*)d_in[2];
    const float* W1 = (const float*)d_in[3];
    const float* b1 = (const float*)d_in[4];
    const float* W2 = (const float*)d_in[5];
    const float* b2 = (const float*)d_in[6];
    float* out = (float*)d_out;

    // ws layout: temp[E*64] bf16 | epos[E] | hist[N] | starts[N] | cursor[N] | bsums[64]
    char* ws = (char*)d_ws;
    const size_t tempB    = (size_t)N_EDGES * OUT_DIM * sizeof(ushort); // 102.4 MB
    const size_t eposOff  = tempB;
    const size_t histOff  = eposOff + (size_t)N_EDGES * 4;
    const size_t strOff   = histOff + (size_t)N_NODES * 4;
    const size_t curOff   = strOff + (size_t)N_NODES * 4;
    const size_t bsumOff  = curOff + (size_t)N_NODES * 4;
    const size_t need     = bsumOff + 64 * 4;

    if (ws_size >= need) {
        ushort* temp  = (ushort*)ws;
        int* epos     = (int*)(ws + eposOff);
        int* hist     = (int*)(ws + histOff);
        int* starts   = (int*)(ws + strOff);
        int* cursor   = (int*)(ws + curOff);
        int* bsums    = (int*)(ws + bsumOff);

        hipMemsetAsync(hist, 0, (size_t)N_NODES * 4, stream);
        hist_kernel<<<N_EDGES / 256, 256, 0, stream>>>(ei, hist);
        scan1_kernel<<<SCAN_NB, SCAN_B, 0, stream>>>(hist, starts, bsums);
        scan3_kernel<<<SCAN_NB, SCAN_B, 0, stream>>>(hist, starts, cursor, bsums);
        fill_kernel<<<N_EDGES / 256, 256, 0, stream>>>(ei, cursor, epos);
        edge_mlp_mfma_kernel<false><<<GRID, THREADS, 0, stream>>>(
            x, ei, ea, W1, b1, W2, b2, out, nullptr, temp, epos);
        pull_kernel<<<(N_NODES + 3) / 4, 256, 0, stream>>>(temp, starts, hist, out);
    } else {
        // fallback: atomic scatter path
        float* cnt = (float*)d_ws;  // N_NODES floats
        zero_kernel<<<(N_NODES * OUT_DIM + 255) / 256, 256, 0, stream>>>(out, cnt);
        edge_mlp_mfma_kernel<true><<<GRID, THREADS, 0, stream>>>(
            x, ei, ea, W1, b1, W2, b2, out, cnt, nullptr, nullptr);
        div_kernel<<<(N_NODES * OUT_DIM + 255) / 256, 256, 0, stream>>>(out, cnt);
    }
}